// Round 3
// baseline (253.387 us; speedup 1.0000x reference)
//
#include <hip/hip_runtime.h>

#define M1         33                     // LPC_ORDER + 1
#define BLK        128                    // threads per block = rows per tile
#define TILE_ELEMS (BLK * M1)             // 4224 floats = 16.5 KB
#define TILE_VEC4  (TILE_ELEMS / 4)       // 1056 float4
#define VEC_FULL   (TILE_VEC4 / BLK)      // 8 full float4 per thread
#define VEC_REM    (TILE_VEC4 - VEC_FULL * BLK)  // 32 remainder float4
#define NBLK       1024                   // persistent grid: 4 blocks/CU

typedef __attribute__((address_space(3))) void  lds_void_t;
typedef const __attribute__((address_space(1))) void gbl_void_t;

// async global->LDS, 16B per lane. gsrc includes the per-lane offset; LDS dest
// layout is wave-uniform base + lane*16 (flat contiguous, lane order = addr order).
__device__ __forceinline__ void gll16(const float4* gsrc, float4* ldsdst) {
    __builtin_amdgcn_global_load_lds((gbl_void_t*)gsrc, (lds_void_t*)ldsdst, 16, 0, 0);
}

__device__ __forceinline__ void prefetch_tile(const float* __restrict__ k,
                                              float* lbuf, size_t tile, int tid) {
    const float4* g = (const float4*)(k + tile * TILE_ELEMS);
    float4* l = (float4*)lbuf;
    #pragma unroll
    for (int i = 0; i < VEC_FULL; ++i)
        gll16(g + i * BLK + tid, l + i * BLK + tid);
    if (tid < VEC_REM)
        gll16(g + VEC_FULL * BLK + tid, l + VEC_FULL * BLK + tid);
}

__global__ __launch_bounds__(BLK)
void parcor_persist_kernel(const float* __restrict__ k, float* __restrict__ out,
                           int ntiles) {
    __shared__ float buf[2][TILE_ELEMS];   // 33.8 KB -> 4 blocks/CU
    const int tid = threadIdx.x;

    // ---- prologue: async prefetch of first tile into buf[0] ----
    const int t0 = blockIdx.x;
    if (t0 < ntiles)
        prefetch_tile(k, buf[0], (size_t)t0, tid);

    float4 st[VEC_FULL];          // deferred store data (previous tile's results)
    float4 st_rem;
    float* st_base = nullptr;     // deferred store destination (null = nothing pending)

    int parity = 0;
    for (int t = t0; t < ntiles; t += NBLK, parity ^= 1) {
        // top barrier: drains gll(tile t) -> buf[parity] ready.
        // Also drains prev stores (issued a full iteration ago -> latency hidden).
        __syncthreads();

        // ---- issue async prefetch of the NEXT tile immediately, so it is in
        //      flight during the entire compute phase ----
        const int tn = t + NBLK;
        if (tn < ntiles)
            prefetch_tile(k, buf[parity ^ 1], (size_t)tn, tid);

        // ---- flush deferred stores of the previous tile (fire-and-forget,
        //      overlapped with compute; acks drain at NEXT top barrier) ----
        if (st_base) {
            float4* gd = (float4*)st_base;
            #pragma unroll
            for (int i = 0; i < VEC_FULL; ++i)
                gd[i * BLK + tid] = st[i];
            if (tid < VEC_REM)
                gd[VEC_FULL * BLK + tid] = st_rem;
        }

        // ---- compute on buf[parity]: own row in registers ----
        float* cur = buf[parity];
        float a[M1];
        #pragma unroll
        for (int j = 0; j < M1; ++j)
            a[j] = cur[tid * M1 + j];   // stride 33 -> 2-way bank alias, free

        #pragma unroll
        for (int m = 2; m < M1; ++m) {
            const float km = a[m];
            #pragma unroll
            for (int j = 1; 2 * j < m; ++j) {
                const float x = a[j];
                const float y = a[m - j];
                a[j]     = fmaf(km, y, x);
                a[m - j] = fmaf(km, x, y);
            }
            if ((m & 1) == 0) {
                const int j = m >> 1;
                a[j] = fmaf(km, a[j], a[j]);   // a[j] * (1 + km)
            }
        }

        #pragma unroll
        for (int j = 0; j < M1; ++j)
            cur[tid * M1 + j] = a[j];   // own row only

        // bottom barrier: rows final in cur (cross-thread for coalesced read);
        // prefetch gll has had the whole compute phase to land.
        __syncthreads();

        // ---- stage coalesced store data into registers; the global_store is
        //      deferred to after the next top barrier ----
        float4* l4 = (float4*)cur;
        #pragma unroll
        for (int i = 0; i < VEC_FULL; ++i)
            st[i] = l4[i * BLK + tid];
        if (tid < VEC_REM)
            st_rem = l4[VEC_FULL * BLK + tid];
        st_base = out + (size_t)t * TILE_ELEMS;
    }

    // ---- epilogue: flush the last tile's deferred stores ----
    if (st_base) {
        float4* gd = (float4*)st_base;
        #pragma unroll
        for (int i = 0; i < VEC_FULL; ++i)
            gd[i * BLK + tid] = st[i];
        if (tid < VEC_REM)
            gd[VEC_FULL * BLK + tid] = st_rem;
    }
}

// Fallback for a row-count not divisible by BLK (not hit for the 16x65536 shape).
__global__ void parcor_to_lpc_tail_kernel(const float* __restrict__ k,
                                          float* __restrict__ out,
                                          int row_start, int nrows) {
    const int row = row_start + blockIdx.x * blockDim.x + threadIdx.x;
    if (row >= nrows) return;
    const float* src = k + (size_t)row * M1;
    float* dst = out + (size_t)row * M1;
    float a[M1];
    #pragma unroll
    for (int j = 0; j < M1; ++j) a[j] = src[j];
    #pragma unroll
    for (int m = 2; m < M1; ++m) {
        const float km = a[m];
        #pragma unroll
        for (int j = 1; 2 * j < m; ++j) {
            const float x = a[j];
            const float y = a[m - j];
            a[j]     = fmaf(km, y, x);
            a[m - j] = fmaf(km, x, y);
        }
        if ((m & 1) == 0) {
            const int j = m >> 1;
            a[j] = fmaf(km, a[j], a[j]);
        }
    }
    #pragma unroll
    for (int j = 0; j < M1; ++j) dst[j] = a[j];
}

extern "C" void kernel_launch(void* const* d_in, const int* in_sizes, int n_in,
                              void* d_out, int out_size, void* d_ws, size_t ws_size,
                              hipStream_t stream) {
    const float* k = (const float*)d_in[0];
    float* out = (float*)d_out;

    const int nrows  = in_sizes[0] / M1;     // 16 * 65536 = 1,048,576
    const int ntiles = nrows / BLK;          // 8192 tiles of 128 rows
    const int rem    = nrows - ntiles * BLK;

    if (ntiles > 0) {
        const int grid = ntiles < NBLK ? ntiles : NBLK;
        parcor_persist_kernel<<<grid, BLK, 0, stream>>>(k, out, ntiles);
    }
    if (rem > 0)
        parcor_to_lpc_tail_kernel<<<(rem + 255) / 256, 256, 0, stream>>>(
            k, out, ntiles * BLK, nrows);
}